// Round 2
// baseline (225.162 us; speedup 1.0000x reference)
//
#include <hip/hip_runtime.h>

typedef unsigned short u16;
typedef __bf16 bf16x8 __attribute__((ext_vector_type(8)));
typedef float  f32x16 __attribute__((ext_vector_type(16)));

__device__ __forceinline__ u16 f2bf(float f) {
    union { float f; unsigned u; } v; v.f = f;
    return (u16)((v.u + 0x7fffu + ((v.u >> 16) & 1u)) >> 16);
}

// ---------------------------------------------------------------------------
// 1) s_raw[b][c] = w[b] @ mod_w[c] + mod_b[c]   (one wave per output, coalesced)
// ---------------------------------------------------------------------------
__global__ __launch_bounds__(256) void lin_kernel(
    const float* __restrict__ w, const float* __restrict__ mod_w,
    const float* __restrict__ mod_b, float* __restrict__ s_raw)
{
    int gw = (blockIdx.x * 256 + threadIdx.x) >> 6;   // 0..8191 = b*512+c
    int lane = threadIdx.x & 63;
    int b = gw >> 9, c = gw & 511;
    const float* wr = w + b * 512;
    const float* mr = mod_w + (size_t)c * 512;
    float a = 0.f;
#pragma unroll
    for (int i = 0; i < 8; ++i)
        a = fmaf(wr[lane + i * 64], mr[lane + i * 64], a);
    for (int off = 32; off; off >>= 1) a += __shfl_down(a, off);
    if (!lane) s_raw[gw] = a + mod_b[c];
}

// ---------------------------------------------------------------------------
// 2) s_eff = LeakyReLU(LN(s_raw)) * scale     (one block per batch row)
// ---------------------------------------------------------------------------
__global__ __launch_bounds__(512) void norm_kernel(
    const float* __restrict__ s_raw, const float* __restrict__ ln_g,
    const float* __restrict__ ln_b, const float* __restrict__ scale,
    float* __restrict__ s_eff)
{
    int b = blockIdx.x, c = threadIdx.x;
    __shared__ float rs[512], rq[512];
    float s = s_raw[b * 512 + c];
    rs[c] = s; rq[c] = s * s;
    __syncthreads();
    for (int off = 256; off; off >>= 1) {
        if (c < off) { rs[c] += rs[c + off]; rq[c] += rq[c + off]; }
        __syncthreads();
    }
    float mean = rs[0] * (1.f / 512.f);
    float var  = rq[0] * (1.f / 512.f) - mean * mean;
    float sn = (s - mean) * rsqrtf(var + 1e-5f) * ln_g[c] + ln_b[c];
    sn = sn >= 0.f ? sn : 0.2f * sn;
    s_eff[b * 512 + c] = sn * scale[c];
}

// ---------------------------------------------------------------------------
// 3) wsq[co][ci] = sum_p weight^2 ; wbfT[((p*64+cg)*512+co)*8+cj] = bf16(w)
// ---------------------------------------------------------------------------
__global__ __launch_bounds__(256) void wsq_kernel(
    const float* __restrict__ weight, float* __restrict__ wsq, u16* __restrict__ wbfT)
{
    int idx = blockIdx.x * 256 + threadIdx.x;      // co*512+ci
    int co = idx >> 9, ci = idx & 511;
    int cg = ci >> 3, cj = ci & 7;
    const float* wp = weight + (size_t)idx * 9;
    float s = 0.f;
#pragma unroll
    for (int p = 0; p < 9; ++p) {
        float v = wp[p];
        s += v * v;
        wbfT[((size_t)(p * 64 + cg) * 512 + co) * 8 + cj] = f2bf(v);
    }
    wsq[idx] = s;
}

// ---------------------------------------------------------------------------
// 4) xs[b][h][w][c] (NHWC bf16) = bf16(x[b][c][h][w] * s_eff[b][c])
// ---------------------------------------------------------------------------
__global__ __launch_bounds__(256) void xs_kernel(
    const float* __restrict__ x, const float* __restrict__ s_eff,
    u16* __restrict__ xs)
{
    const int bh = blockIdx.x;
    const int b = bh >> 5, h = bh & 31;
    __shared__ float tile[64][33];
    for (int c0 = 0; c0 < 512; c0 += 64) {
        if (c0) __syncthreads();
        for (int idx = threadIdx.x; idx < 2048; idx += 256) {
            int c = idx >> 5, ww = idx & 31;
            tile[c][ww] = x[(((size_t)b * 512 + c0 + c) * 32 + h) * 32 + ww]
                          * s_eff[b * 512 + c0 + c];
        }
        __syncthreads();
        for (int idx = threadIdx.x; idx < 2048; idx += 256) {
            int ww = idx >> 6, c = idx & 63;
            xs[((b * 32 + h) * 32 + ww) * 512 + c0 + c] = f2bf(tile[c][ww]);
        }
    }
}

// ---------------------------------------------------------------------------
// 5) dsc[b][o] = rsqrt(sum_i s_eff[b][i]^2 * wsq[o][i] + 1e-8)
// ---------------------------------------------------------------------------
__global__ __launch_bounds__(256) void dsc_kernel(
    const float* __restrict__ s_eff, const float* __restrict__ wsq,
    float* __restrict__ dsc)
{
    int gw = (blockIdx.x * 256 + threadIdx.x) >> 6;   // b*512+cout
    int lane = threadIdx.x & 63;
    int b = gw >> 9, co = gw & 511;
    float a = 0.f;
#pragma unroll
    for (int i = 0; i < 8; ++i) {
        int cin = lane + i * 64;
        float se = s_eff[b * 512 + cin];
        a += se * se * wsq[co * 512 + cin];
    }
    for (int off = 32; off; off >>= 1) a += __shfl_down(a, off);
    if (!lane) dsc[gw] = rsqrtf(a + 1e-8f);
}

// ---------------------------------------------------------------------------
// 6) conv: implicit-GEMM, mfma_f32_32x32x16_bf16.
//    grid 512 = 4 cout-tiles (XCD-pinned) x 128 px-tiles (b, 4-row strip)
//    block 256 thr = 4 waves (2M x 2N); wave tile 64 cout x 64 px (2 rows)
//    LDS: x strip [204 pos][32 cin] u16, XOR-swizzled, double-buffered,
//    ONE barrier per 32-cin round; weights (a-frags) straight from L2,
//    coalesced via transposed wbfT layout.
// ---------------------------------------------------------------------------
__global__ __launch_bounds__(256, 2) void conv_kernel(
    const u16* __restrict__ wbfT,  // [9][64][512][8]
    const u16* __restrict__ xs,    // [16][32][32][512]
    const float* __restrict__ dsc, // [16][512]
    float* __restrict__ out)       // [16][512][32][32]
{
    __shared__ __align__(16) u16 lds[2][204 * 32];   // 13056 B each

    const int tid  = threadIdx.x;
    const int lane = tid & 63;
    const int wv   = tid >> 6;       // 0..3
    const int wm   = wv >> 1;        // 0..1 (M)
    const int wn   = wv & 1;         // 0..1 (N: 2 rows each)
    const int l31  = lane & 31;
    const int kc8  = lane >> 5;      // k-chunk half

    const int bx  = blockIdx.x;
    const int mt  = bx & 3;          // cout tile; XCD = bx&7 -> mt fixed per XCD
    const int pxt = bx >> 2;         // 0..127
    const int b   = pxt >> 3;
    const int h0  = (pxt & 7) << 2;  // output rows h0..h0+3

    const u16* xsb = xs + (size_t)b * (32 * 32 * 512);

    // ---- staging descriptors: 816 chunks = 204 positions x 4 x 16B ----
    int soff[4], loff[4];
    bool svalid[4], inb[4];
#pragma unroll
    for (int k = 0; k < 4; ++k) {
        int ch = tid + k * 256;
        int p = ch >> 2, c = ch & 3;
        int rr = p / 34, cc = p % 34;
        int h = h0 - 1 + rr;
        int w = cc - 1;
        svalid[k] = (ch < 816);
        inb[k] = svalid[k] && ((unsigned)h < 32u) && ((unsigned)w < 32u);
        soff[k] = (h * 32 + w) * 512 + c * 8;                     // elements
        loff[k] = p * 64 + ((c ^ ((p >> 1) & 3)) << 4);           // bytes
    }

    uint4 pf[4];
    auto prefetch = [&](int c0) {
#pragma unroll
        for (int k = 0; k < 4; ++k) {
            uint4 t = {0u, 0u, 0u, 0u};
            if (inb[k]) t = *reinterpret_cast<const uint4*>(xsb + soff[k] + c0);
            pf[k] = t;
        }
    };
    auto commit = [&](int buf) {
#pragma unroll
        for (int k = 0; k < 4; ++k)
            if (svalid[k])
                *reinterpret_cast<uint4*>((char*)lds[buf] + loff[k]) = pf[k];
    };

    // ---- a-frag base: coalesced, lane l31 -> cout, kc8 -> k-half ----
    const int co_w = mt * 128 + wm * 64;
    const u16* wa = wbfT + (size_t)(co_w + l31) * 8 + (size_t)kc8 * 4096;

    f32x16 acc[2][2] = {};

    prefetch(0);
    commit(0);
    __syncthreads();

    for (int r = 0; r < 16; ++r) {
        const int c0 = r * 32;
        if (r < 15) prefetch(c0 + 32);
        const u16* war = wa + (size_t)(c0 >> 3) * 4096;
        const char* ldsc = (const char*)lds[r & 1];

#pragma unroll
        for (int pos = 0; pos < 9; ++pos) {
            const int kh = pos / 3, kw = pos % 3;
#pragma unroll
            for (int kk = 0; kk < 2; ++kk) {          // k0 = kk*16
                bf16x8 a0 = *reinterpret_cast<const bf16x8*>(
                    war + pos * 262144 + kk * 8192);
                bf16x8 a1 = *reinterpret_cast<const bf16x8*>(
                    war + pos * 262144 + kk * 8192 + 256);
                int p0 = (wn * 2 + kh) * 34 + l31 + kw;
                int p1 = p0 + 34;
                int c2 = kk * 2 + kc8;
                bf16x8 b0 = *reinterpret_cast<const bf16x8*>(
                    ldsc + p0 * 64 + ((c2 ^ ((p0 >> 1) & 3)) << 4));
                bf16x8 b1 = *reinterpret_cast<const bf16x8*>(
                    ldsc + p1 * 64 + ((c2 ^ ((p1 >> 1) & 3)) << 4));
                acc[0][0] = __builtin_amdgcn_mfma_f32_32x32x16_bf16(a0, b0, acc[0][0], 0, 0, 0);
                acc[0][1] = __builtin_amdgcn_mfma_f32_32x32x16_bf16(a0, b1, acc[0][1], 0, 0, 0);
                acc[1][0] = __builtin_amdgcn_mfma_f32_32x32x16_bf16(a1, b0, acc[1][0], 0, 0, 0);
                acc[1][1] = __builtin_amdgcn_mfma_f32_32x32x16_bf16(a1, b1, acc[1][1], 0, 0, 0);
            }
        }
        if (r < 15) commit((r + 1) & 1);
        __syncthreads();
    }

    // ---- epilogue: C/D layout col=lane&31, row=(q&3)+8*(q>>2)+4*(lane>>5) ----
#pragma unroll
    for (int mf = 0; mf < 2; ++mf) {
#pragma unroll
        for (int nf = 0; nf < 2; ++nf) {
            const int h = h0 + wn * 2 + nf;
#pragma unroll
            for (int q = 0; q < 16; ++q) {
                int row = (q & 3) + 8 * (q >> 2) + 4 * kc8;
                int co = co_w + mf * 32 + row;
                float d = dsc[b * 512 + co];
                out[(((size_t)b * 512 + co) * 32 + h) * 32 + l31]
                    = acc[mf][nf][q] * d;
            }
        }
    }
}

// ---------------------------------------------------------------------------
extern "C" void kernel_launch(void* const* d_in, const int* in_sizes, int n_in,
                              void* d_out, int out_size, void* d_ws, size_t ws_size,
                              hipStream_t stream) {
    const float* x      = (const float*)d_in[0];
    const float* w      = (const float*)d_in[1];
    const float* mod_w  = (const float*)d_in[2];
    const float* mod_b  = (const float*)d_in[3];
    const float* ln_g   = (const float*)d_in[4];
    const float* ln_b   = (const float*)d_in[5];
    const float* weight = (const float*)d_in[6];
    const float* scale  = (const float*)d_in[7];
    float* out = (float*)d_out;

    char* ws = (char*)d_ws;
    float* s_raw = (float*)(ws);                     // 32 KB (aliased w/ dsc)
    float* dsc   = (float*)(ws);                     // reused after norm
    float* s_eff = (float*)(ws + 32768);             // 32 KB
    float* wsq   = (float*)(ws + 65536);             // 1 MB
    u16*   wbfT  = (u16*)(ws + 65536 + 1048576);     // 4.5 MB
    u16*   xs    = (u16*)(ws + 65536 + 1048576 + 4718592);  // 16.78 MB
    if (ws_size < 22609920u) return;

    lin_kernel <<<2048, 256, 0, stream>>>(w, mod_w, mod_b, s_raw);
    wsq_kernel <<<1024, 256, 0, stream>>>(weight, wsq, wbfT);
    norm_kernel<<<16, 512, 0, stream>>>(s_raw, ln_g, ln_b, scale, s_eff);
    xs_kernel  <<<512, 256, 0, stream>>>(x, s_eff, xs);
    dsc_kernel <<<2048, 256, 0, stream>>>(s_eff, wsq, dsc);
    conv_kernel<<<512, 256, 0, stream>>>(wbfT, xs, dsc, out);
}

// Round 3
// 163.349 us; speedup vs baseline: 1.3784x; 1.3784x over previous
//
#include <hip/hip_runtime.h>

typedef unsigned short u16;
typedef __bf16 bf16x8 __attribute__((ext_vector_type(8)));
typedef float  f32x16 __attribute__((ext_vector_type(16)));

__device__ __forceinline__ u16 f2bf(float f) {
    union { float f; unsigned u; } v; v.f = f;
    return (u16)((v.u + 0x7fffu + ((v.u >> 16) & 1u)) >> 16);
}

// async global->LDS, 16B per lane, linear LDS dest (wave-uniform base + lane*16)
#define GLD16(gsrc, ldst) \
    __builtin_amdgcn_global_load_lds( \
        (const __attribute__((address_space(1))) void*)(gsrc), \
        (__attribute__((address_space(3))) void*)(ldst), 16, 0, 0)

// ---------------------------------------------------------------------------
// 1) s_raw[b][c] = w[b] @ mod_w[c] + mod_b[c]
// ---------------------------------------------------------------------------
__global__ __launch_bounds__(256) void lin_kernel(
    const float* __restrict__ w, const float* __restrict__ mod_w,
    const float* __restrict__ mod_b, float* __restrict__ s_raw)
{
    int gw = (blockIdx.x * 256 + threadIdx.x) >> 6;
    int lane = threadIdx.x & 63;
    int b = gw >> 9, c = gw & 511;
    const float* wr = w + b * 512;
    const float* mr = mod_w + (size_t)c * 512;
    float a = 0.f;
#pragma unroll
    for (int i = 0; i < 8; ++i)
        a = fmaf(wr[lane + i * 64], mr[lane + i * 64], a);
    for (int off = 32; off; off >>= 1) a += __shfl_down(a, off);
    if (!lane) s_raw[gw] = a + mod_b[c];
}

// ---------------------------------------------------------------------------
// 2) s_eff = LeakyReLU(LN(s_raw)) * scale
// ---------------------------------------------------------------------------
__global__ __launch_bounds__(512) void norm_kernel(
    const float* __restrict__ s_raw, const float* __restrict__ ln_g,
    const float* __restrict__ ln_b, const float* __restrict__ scale,
    float* __restrict__ s_eff)
{
    int b = blockIdx.x, c = threadIdx.x;
    __shared__ float rs[512], rq[512];
    float s = s_raw[b * 512 + c];
    rs[c] = s; rq[c] = s * s;
    __syncthreads();
    for (int off = 256; off; off >>= 1) {
        if (c < off) { rs[c] += rs[c + off]; rq[c] += rq[c + off]; }
        __syncthreads();
    }
    float mean = rs[0] * (1.f / 512.f);
    float var  = rq[0] * (1.f / 512.f) - mean * mean;
    float sn = (s - mean) * rsqrtf(var + 1e-5f) * ln_g[c] + ln_b[c];
    sn = sn >= 0.f ? sn : 0.2f * sn;
    s_eff[b * 512 + c] = sn * scale[c];
}

// ---------------------------------------------------------------------------
// 3) wsq[co][ci] = sum_p weight^2 ; wbfT[(p*64+cg)*512*8 + co*8 + cj] = bf16(w)
// ---------------------------------------------------------------------------
__global__ __launch_bounds__(256) void wsq_kernel(
    const float* __restrict__ weight, float* __restrict__ wsq, u16* __restrict__ wbfT)
{
    int idx = blockIdx.x * 256 + threadIdx.x;      // co*512+ci
    int co = idx >> 9, ci = idx & 511;
    int cg = ci >> 3, cj = ci & 7;
    const float* wp = weight + (size_t)idx * 9;
    float s = 0.f;
#pragma unroll
    for (int p = 0; p < 9; ++p) {
        float v = wp[p];
        s += v * v;
        wbfT[((size_t)(p * 64 + cg) * 512 + co) * 8 + cj] = f2bf(v);
    }
    wsq[idx] = s;
}

// ---------------------------------------------------------------------------
// 4) xs[b][h][w][c] (NHWC bf16) = bf16(x[b][c][h][w] * s_eff[b][c])
// ---------------------------------------------------------------------------
__global__ __launch_bounds__(256) void xs_kernel(
    const float* __restrict__ x, const float* __restrict__ s_eff,
    u16* __restrict__ xs)
{
    const int bh = blockIdx.x;
    const int b = bh >> 5, h = bh & 31;
    __shared__ float tile[64][33];
    for (int c0 = 0; c0 < 512; c0 += 64) {
        if (c0) __syncthreads();
        for (int idx = threadIdx.x; idx < 2048; idx += 256) {
            int c = idx >> 5, ww = idx & 31;
            tile[c][ww] = x[(((size_t)b * 512 + c0 + c) * 32 + h) * 32 + ww]
                          * s_eff[b * 512 + c0 + c];
        }
        __syncthreads();
        for (int idx = threadIdx.x; idx < 2048; idx += 256) {
            int ww = idx >> 6, c = idx & 63;
            xs[((b * 32 + h) * 32 + ww) * 512 + c0 + c] = f2bf(tile[c][ww]);
        }
    }
}

// ---------------------------------------------------------------------------
// 5) dsc[b][o] = rsqrt(sum_i s_eff[b][i]^2 * wsq[o][i] + 1e-8)
// ---------------------------------------------------------------------------
__global__ __launch_bounds__(256) void dsc_kernel(
    const float* __restrict__ s_eff, const float* __restrict__ wsq,
    float* __restrict__ dsc)
{
    int gw = (blockIdx.x * 256 + threadIdx.x) >> 6;
    int lane = threadIdx.x & 63;
    int b = gw >> 9, co = gw & 511;
    float a = 0.f;
#pragma unroll
    for (int i = 0; i < 8; ++i) {
        int cin = lane + i * 64;
        float se = s_eff[b * 512 + cin];
        a += se * se * wsq[co * 512 + cin];
    }
    for (int off = 32; off; off >>= 1) a += __shfl_down(a, off);
    if (!lane) dsc[gw] = rsqrtf(a + 1e-8f);
}

// ---------------------------------------------------------------------------
// 6) zero 4KB (zeros page for halo OOB lanes)
// ---------------------------------------------------------------------------
__global__ void zfill_kernel(float* p) { p[threadIdx.x] = 0.f; }

// ---------------------------------------------------------------------------
// 7) conv as flat GEMM M=512 x N=16384 x K=4608 (pos-major K), m97/T3 2-phase.
//    512 blocks (mt=bx&3 pinned per XCD, nt=bx>>2), 256 thr = 4 waves 64x64.
//    Per K-step (32 cin): A-tile 8KB + B-tile 8KB via global_load_lds(16B),
//    double-buffered, ONE barrier per step. Halo OOB lanes read zeros page.
//    LDS slot swizzle: chunk(row,slot) holds kc = slot ^ (row&3), both sides.
// ---------------------------------------------------------------------------
__global__ __launch_bounds__(256) void conv_kernel(
    const u16* __restrict__ wbfT,  // [576 kflat8][512 co][8]
    const u16* __restrict__ xs,    // [16][32][32][512]
    const float* __restrict__ dsc, // [16][512]
    const u16* __restrict__ zp,    // >=16B zeros
    float* __restrict__ out)       // [16][512][32][32]
{
    __shared__ __align__(16) u16 lds[2][8192];   // per buf: A 8KB | B 8KB

    const int tid  = threadIdx.x;
    const int lane = tid & 63;
    const int wv   = tid >> 6;       // 0..3
    const int wm   = wv >> 1;        // cout half
    const int wn   = wv & 1;         // px half
    const int l31  = lane & 31;
    const int kc8  = lane >> 5;

    const int bx = blockIdx.x;
    const int mt = bx & 3;           // cout tile, pinned per XCD (bx%8)
    const int nt = bx >> 2;          // 0..127
    const int b  = nt >> 3;
    const int h0 = (nt & 7) << 2;

    const u16* xsb = xs + (size_t)b * (32 * 32 * 512);

    // A staging: chunk ch -> (co=ch>>2, slot=ch&3) holds kc = slot^(co&3);
    // source advances +16384 u16 per K-step (4 kflat8 chunks of 4096 u16).
    const u16* aptr[2];
#pragma unroll
    for (int j = 0; j < 2; ++j) {
        int ch = tid + j * 256;
        int co = ch >> 2;
        int kc = (ch & 3) ^ (co & 3);
        aptr[j] = wbfT + (size_t)kc * 4096 + (size_t)(mt * 128 + co) * 8;
    }
    // B chunk descriptors (base recomputed when pos changes)
    const int bnn0 = tid >> 2,               bnn1 = (tid + 256) >> 2;
    const int bkc0 = (tid & 3) ^ (bnn0 & 3), bkc1 = ((tid + 256) & 3) ^ (bnn1 & 3);
    const u16* bbase0; const u16* bbase1;
    bool bval0, bval1;

    auto setB = [&](int pos) {
        int kh = pos / 3 - 1, kw = pos % 3 - 1;
        int hh0 = h0 + (bnn0 >> 5) + kh, ww0 = (bnn0 & 31) + kw;
        int hh1 = h0 + (bnn1 >> 5) + kh, ww1 = (bnn1 & 31) + kw;
        bval0 = ((unsigned)hh0 < 32u) & ((unsigned)ww0 < 32u);
        bval1 = ((unsigned)hh1 < 32u) & ((unsigned)ww1 < 32u);
        bbase0 = xsb + (hh0 * 32 + ww0) * 512 + bkc0 * 8;
        bbase1 = xsb + (hh1 * 32 + ww1) * 512 + bkc1 * 8;
    };

    char* ldsb = (char*)lds;
    char* wbase = ldsb + wv * 1024;   // wave-uniform; HW adds lane*16

    auto stage = [&](int buf, int c0) {
        char* d = wbase + buf * 16384;
        GLD16(aptr[0], d);
        GLD16(aptr[1], d + 4096);
        const u16* p0 = bval0 ? bbase0 + c0 : zp;
        const u16* p1 = bval1 ? bbase1 + c0 : zp;
        GLD16(p0, d + 8192);
        GLD16(p1, d + 12288);
        aptr[0] += 16384; aptr[1] += 16384;
    };

    f32x16 acc[2][2] = {};

    setB(0);
    stage(0, 0);
    __syncthreads();   // drains vmcnt(0): buf0 ready

    for (int s = 0; s < 144; ++s) {
        const int cur = s & 1;
        if (s + 1 < 144) {
            const int sn = s + 1;
            if ((sn & 15) == 0) setB(sn >> 4);
            stage(cur ^ 1, (sn & 15) * 32);   // loads fly over the MFMA phase
        }
        const char* base = ldsb + cur * 16384;
#pragma unroll
        for (int kk = 0; kk < 2; ++kk) {
            const int slot = ((kk * 2 + kc8) ^ (l31 & 3)) * 16;
            const char* arow = base + (wm * 64 + l31) * 64 + slot;
            const char* brow = base + 8192 + (wn * 64 + l31) * 64 + slot;
            bf16x8 a0 = *(const bf16x8*)(arow);
            bf16x8 a1 = *(const bf16x8*)(arow + 2048);
            bf16x8 b0 = *(const bf16x8*)(brow);
            bf16x8 b1 = *(const bf16x8*)(brow + 2048);
            acc[0][0] = __builtin_amdgcn_mfma_f32_32x32x16_bf16(a0, b0, acc[0][0], 0, 0, 0);
            acc[0][1] = __builtin_amdgcn_mfma_f32_32x32x16_bf16(a0, b1, acc[0][1], 0, 0, 0);
            acc[1][0] = __builtin_amdgcn_mfma_f32_32x32x16_bf16(a1, b0, acc[1][0], 0, 0, 0);
            acc[1][1] = __builtin_amdgcn_mfma_f32_32x32x16_bf16(a1, b1, acc[1][1], 0, 0, 0);
        }
        __syncthreads();   // next stage's buf free + this iter's loads drained
    }

    // epilogue: C/D layout col=lane&31, row=(q&3)+8*(q>>2)+4*(lane>>5)
    const float* db = dsc + b * 512;
#pragma unroll
    for (int mf = 0; mf < 2; ++mf) {
#pragma unroll
        for (int nf = 0; nf < 2; ++nf) {
            const int n = nt * 128 + wn * 64 + nf * 32 + l31;
            const int h = (n >> 5) & 31, w = n & 31;
#pragma unroll
            for (int q = 0; q < 16; ++q) {
                int row = (q & 3) + 8 * (q >> 2) + 4 * kc8;
                int co  = mt * 128 + wm * 64 + mf * 32 + row;
                out[(((size_t)b * 512 + co) * 32 + h) * 32 + w]
                    = acc[mf][nf][q] * db[co];
            }
        }
    }
}

// ---------------------------------------------------------------------------
extern "C" void kernel_launch(void* const* d_in, const int* in_sizes, int n_in,
                              void* d_out, int out_size, void* d_ws, size_t ws_size,
                              hipStream_t stream) {
    const float* x      = (const float*)d_in[0];
    const float* w      = (const float*)d_in[1];
    const float* mod_w  = (const float*)d_in[2];
    const float* mod_b  = (const float*)d_in[3];
    const float* ln_g   = (const float*)d_in[4];
    const float* ln_b   = (const float*)d_in[5];
    const float* weight = (const float*)d_in[6];
    const float* scale  = (const float*)d_in[7];
    float* out = (float*)d_out;

    char* ws = (char*)d_ws;
    float* s_raw = (float*)(ws);                     // 32 KB, reused as dsc
    float* dsc   = (float*)(ws);
    float* s_eff = (float*)(ws + 32768);             // 32 KB; tail reused as zeros page
    float* wsq   = (float*)(ws + 65536);             // 1 MB
    u16*   wbfT  = (u16*)(ws + 65536 + 1048576);     // 4.5 MB
    u16*   xs    = (u16*)(ws + 65536 + 1048576 + 4718592);  // 16.78 MB
    if (ws_size < 22609920u) return;

    lin_kernel <<<2048, 256, 0, stream>>>(w, mod_w, mod_b, s_raw);
    wsq_kernel <<<1024, 256, 0, stream>>>(weight, wsq, wbfT);
    norm_kernel<<<16, 512, 0, stream>>>(s_raw, ln_g, ln_b, scale, s_eff);
    xs_kernel  <<<512, 256, 0, stream>>>(x, s_eff, xs);
    dsc_kernel <<<2048, 256, 0, stream>>>(s_eff, wsq, dsc);
    // s_eff no longer needed: zero its first 4KB as the halo zeros page
    zfill_kernel<<<1, 1024, 0, stream>>>(s_eff);
    conv_kernel<<<512, 256, 0, stream>>>(wbfT, xs, dsc, (const u16*)s_eff, out);
}